// Round 15
// baseline (95.582 us; speedup 1.0000x reference)
//
#include <hip/hip_runtime.h>

#define N_SP 3136   // H*W = 49*64
#define C_CH 256
#define CQ   32
#define NB   4
#define JT   64     // attn j-tile
#define NJT  49     // j-tiles (exact)
#define QT   128    // attn q-tile (25 tiles, q padded to 3200)
#define NQT  25
#define JSPL 4      // j-splits per q-tile -> 400 attn blocks
// 1 / (exp(sqrt(3))*sqrt(3136/256) + 2*sqrt(6))
#define INV_BOUND 0.04051569f
#define LOG2E 1.44269504f

typedef __attribute__((ext_vector_type(8))) short bf16x8;
typedef __attribute__((ext_vector_type(4))) float f32x4;
typedef __attribute__((ext_vector_type(2))) long long l64x2;
typedef unsigned short u16;
typedef unsigned int   u32;
typedef unsigned char  u8;
typedef long long      l64;

#define MFMA16(a,b,c) __builtin_amdgcn_mfma_f32_16x16x32_bf16(a,b,c,0,0,0)
#define MFMA8(a,b,c)  __builtin_amdgcn_mfma_f32_16x16x32_bf8_fp8(a,b,c,0,0,0)

__device__ __forceinline__ u16 f2b(float f) {
    u32 u = __builtin_bit_cast(u32, f);
    u += 0x7fffu + ((u >> 16) & 1u);   // RTNE
    return (u16)(u >> 16);
}
__device__ __forceinline__ float b2f(u16 v) {
    return __builtin_bit_cast(float, (u32)v << 16);
}
__device__ __forceinline__ u8 f2fp8(float f) {
    return (u8)(__builtin_amdgcn_cvt_pk_fp8_f32(f, f, 0, false) & 0xff);
}
__device__ __forceinline__ void dma16(const void* g, void* l) {
    __builtin_amdgcn_global_load_lds((const __attribute__((address_space(1))) u32*)g,
                                     (__attribute__((address_space(3))) u32*)l, 16, 0, 0);
}
__device__ __forceinline__ void dma4(const void* g, void* l) {
    __builtin_amdgcn_global_load_lds((const __attribute__((address_space(1))) u32*)g,
                                     (__attribute__((address_space(3))) u32*)l, 4, 0, 0);
}

// ---------------------------------------------------------------------------
// stage1 (verified): xT transpose pre-swizzled, W->bf16 pre-swizzled,
// norm+scale+kmax0.
// ---------------------------------------------------------------------------
__global__ __launch_bounds__(256) void stage1_kernel(
    const float* __restrict__ x, const float* __restrict__ Wq,
    const float* __restrict__ Wk, const float* __restrict__ Wv,
    u8* __restrict__ xT, u8* __restrict__ Wqb, u8* __restrict__ Wkb,
    u8* __restrict__ Wvb, float* __restrict__ scale_out,
    float* __restrict__ kmax)
{
    __shared__ float smem[64 * 65];
    const int t = threadIdx.x;
    const int bid = blockIdx.x;

    if (bid < 784) {
        float (*tile)[65] = (float(*)[65])smem;
        const int ct = bid & 3, nt = (bid >> 2) % 49, b = bid / 196;
        const int c0 = ct * 64, n0 = nt * 64;
        const int cc = t >> 4, nn4 = (t & 15) * 4;
        #pragma unroll
        for (int k = 0; k < 4; ++k) {
            int cl = cc + k * 16;
            float4 v = *(const float4*)(x + (size_t)(b * C_CH + c0 + cl) * N_SP + n0 + nn4);
            tile[cl][nn4] = v.x; tile[cl][nn4 + 1] = v.y;
            tile[cl][nn4 + 2] = v.z; tile[cl][nn4 + 3] = v.w;
        }
        __syncthreads();
        const int c4 = (t & 15) * 4, nn = t >> 4;
        #pragma unroll
        for (int k = 0; k < 4; ++k) {
            int nl = nn + k * 16;
            ushort4 o;
            o.x = f2b(tile[c4 + 0][nl]); o.y = f2b(tile[c4 + 1][nl]);
            o.z = f2b(tile[c4 + 2][nl]); o.w = f2b(tile[c4 + 3][nl]);
            const int off = ((c0 + c4) * 2) ^ ((nl & 15) << 5);
            *(ushort4*)(xT + (size_t)(b * N_SP + n0 + nl) * 512 + off) = o;
        }
    } else if (bid < 864) {
        int idx = (bid - 784) * 256 + t;
        const float* src; u8* dst; int off;
        if (idx < 2048)      { src = Wq; dst = Wqb; off = idx; }
        else if (idx < 4096) { src = Wk; dst = Wkb; off = idx - 2048; }
        else                 { src = Wv; dst = Wvb; off = idx - 4096; }
        float4 v = *(const float4*)(src + off * 4);
        ushort4 o; o.x = f2b(v.x); o.y = f2b(v.y); o.z = f2b(v.z); o.w = f2b(v.w);
        const int row = off >> 6, inner = (off & 63) * 8;
        *(ushort4*)(dst + row * 512 + (inner ^ ((row & 15) << 5))) = o;
    } else {
        if (t < NB) kmax[t] = 0.f;
        float* red = smem;
        float u2 = 0.f;
        for (int i = t; i < CQ * C_CH; i += 256) { float w = Wq[i]; u2 += w * w; }
        red[t] = u2; __syncthreads();
        #pragma unroll
        for (int s = 128; s > 0; s >>= 1) { if (t < s) red[t] += red[t + s]; __syncthreads(); }
        float u2t = red[0]; __syncthreads();
        float vn2 = 0.f;
        for (int o = 0; o < CQ; ++o)   { float w = Wk[o * C_CH + t]; vn2 += w * w; }
        float wn2 = 0.f;
        for (int o = 0; o < C_CH; ++o) { float w = Wv[o * C_CH + t]; wn2 += w * w; }
        red[t] = fmaxf(vn2, wn2); __syncthreads();
        #pragma unroll
        for (int s = 128; s > 0; s >>= 1) { if (t < s) red[t] = fmaxf(red[t], red[t + s]); __syncthreads(); }
        if (t == 0) scale_out[0] = 1.0f / (sqrtf(u2t) * sqrtf(red[0]));
    }
}

// ---------------------------------------------------------------------------
// qkv (verified): DMA-staged x/W tiles -> LDS -> MFMA.
// ---------------------------------------------------------------------------
__global__ __launch_bounds__(256) void qkv_mfma(
    const u8* __restrict__ xT, const u8* __restrict__ Wqb,
    const u8* __restrict__ Wkb, const u8* __restrict__ Wvb,
    const float* __restrict__ bq, const float* __restrict__ bk,
    const float* __restrict__ bv, const float* __restrict__ scale_p,
    u16* __restrict__ qT, u8* __restrict__ Kg, u8* __restrict__ Vg,
    float* __restrict__ qnorm, float* __restrict__ kmax)
{
    __shared__ __align__(16) u8 xTl[32768];
    __shared__ __align__(16) u8 Wl[32768];

    const int t = threadIdx.x;
    const int split = blockIdx.x / 196, tile = blockIdx.x % 196;
    const int b = tile / 49, nt = tile % 49;
    const int w = t >> 6, lane = t & 63, li = t & 15, g = (t >> 4) & 3;
    const int n = nt * 64 + w * 16 + li;
    const int r0 = (split - 1) * 64;
    const f32x4 zero = {0.f, 0.f, 0.f, 0.f};

    {
        const u8* xsrc = xT + (size_t)(b * N_SP + nt * 64) * 512;
        #pragma unroll
        for (int i = 0; i < 8; ++i)
            dma16(xsrc + w * 8192 + i * 1024 + lane * 16, xTl + w * 8192 + i * 1024);
        if (split == 0) {
            #pragma unroll
            for (int i = 0; i < 4; ++i)
                dma16(Wqb + w * 4096 + i * 1024 + lane * 16, Wl + w * 4096 + i * 1024);
            #pragma unroll
            for (int i = 0; i < 4; ++i)
                dma16(Wkb + w * 4096 + i * 1024 + lane * 16, Wl + 16384 + w * 4096 + i * 1024);
        } else {
            const u8* wsrc = Wvb + (size_t)r0 * 512;
            #pragma unroll
            for (int i = 0; i < 8; ++i)
                dma16(wsrc + w * 8192 + i * 1024 + lane * 16, Wl + w * 8192 + i * 1024);
        }
    }
    asm volatile("s_waitcnt vmcnt(0)" ::: "memory");
    __syncthreads();

    const int swz = li << 5;
    bf16x8 xf[8];
    #pragma unroll
    for (int ks = 0; ks < 8; ++ks)
        xf[ks] = *(const bf16x8*)(xTl + (w * 16 + li) * 512 + ((ks * 64 + 16 * g) ^ swz));

    if (split == 0) {
        f32x4 aq0 = zero, aq1 = zero, ak0 = zero, ak1 = zero;
        #pragma unroll
        for (int ks = 0; ks < 8; ++ks) {
            const int o = (ks * 64 + 16 * g) ^ swz;
            bf16x8 w0 = *(const bf16x8*)(Wl + li * 512 + o);
            bf16x8 w1 = *(const bf16x8*)(Wl + (16 + li) * 512 + o);
            bf16x8 w2 = *(const bf16x8*)(Wl + 16384 + li * 512 + o);
            bf16x8 w3 = *(const bf16x8*)(Wl + 16384 + (16 + li) * 512 + o);
            aq0 = MFMA16(w0, xf[ks], aq0);
            aq1 = MFMA16(w1, xf[ks], aq1);
            ak0 = MFMA16(w2, xf[ks], ak0);
            ak1 = MFMA16(w3, xf[ks], ak1);
        }
        const float scf = scale_p[0] * LOG2E;
        f32x4 bq0 = *(const f32x4*)(bq + 4 * g);
        f32x4 bq1 = *(const f32x4*)(bq + 16 + 4 * g);
        f32x4 bk0 = *(const f32x4*)(bk + 4 * g);
        f32x4 bk1 = *(const f32x4*)(bk + 16 + 4 * g);
        float qn2 = 0.f, kn2 = 0.f;
        ushort4 s0, s1;
        #pragma unroll
        for (int r = 0; r < 4; ++r) {
            float q0 = (aq0[r] + bq0[r]) * scf;
            float q1 = (aq1[r] + bq1[r]) * scf;
            qn2 += q0 * q0 + q1 * q1;
            ((u16*)&s0)[r] = f2b(q0); ((u16*)&s1)[r] = f2b(q1);
        }
        *(ushort4*)(qT + (size_t)(b * N_SP + n) * CQ + 4 * g)      = s0;
        *(ushort4*)(qT + (size_t)(b * N_SP + n) * CQ + 16 + 4 * g) = s1;
        #pragma unroll
        for (int r = 0; r < 4; ++r) {
            float k0 = ak0[r] + bk0[r];
            float k1 = ak1[r] + bk1[r];
            kn2 += k0 * k0 + k1 * k1;
            ((u16*)&s0)[r] = f2b(k0); ((u16*)&s1)[r] = f2b(k1);
        }
        u8* krow = Kg + ((size_t)b * N_SP + n) * 64;
        const int swn = ((n >> 1) & 3) << 4;
        *(ushort4*)(krow + ((8 * g) ^ swn))      = s0;
        *(ushort4*)(krow + ((32 + 8 * g) ^ swn)) = s1;

        qn2 += __shfl_xor(qn2, 16); qn2 += __shfl_xor(qn2, 32);
        kn2 += __shfl_xor(kn2, 16); kn2 += __shfl_xor(kn2, 32);
        if (g == 0) qnorm[b * N_SP + n] = sqrtf(qn2);
        float kn = sqrtf(kn2);
        #pragma unroll
        for (int d = 1; d < 16; d <<= 1) kn = fmaxf(kn, __shfl_xor(kn, d));
        if ((t & 63) == 0) atomicMax((int*)(kmax + b), __float_as_int(kn));
    } else {
        f32x4 a[4] = {zero, zero, zero, zero};
        #pragma unroll
        for (int ks = 0; ks < 8; ++ks) {
            const int o = (ks * 64 + 16 * g) ^ swz;
            #pragma unroll
            for (int fr = 0; fr < 4; ++fr) {
                bf16x8 wf = *(const bf16x8*)(Wl + (fr * 16 + li) * 512 + o);
                a[fr] = MFMA16(wf, xf[ks], a[fr]);
            }
        }
        const int jj = w * 16 + li;
        const int p = ((jj >> 5) & 1) * 8 + ((jj >> 3) & 3) * 16 + (jj & 7);
        u8* vtile = Vg + (size_t)(b * NJT + nt) * 16384;
        #pragma unroll
        for (int fr = 0; fr < 4; ++fr) {
            f32x4 bb = *(const f32x4*)(bv + r0 + fr * 16 + 4 * g);
            #pragma unroll
            for (int r = 0; r < 4; ++r) {
                const int c = r0 + fr * 16 + 4 * g + r;
                vtile[c * 64 + (p ^ (((c >> 1) & 3) << 4))] = f2fp8(a[fr][r] + bb[r]);
            }
        }
    }
}

// ---------------------------------------------------------------------------
// Attention main: 400 blocks (4b x 25 q-tiles of 128 x 4 j-splits) x 512 thr,
// launch_bounds(512,4) + 68KB LDS -> 2 blocks/CU. Ring-3 depth-2 DMA,
// vmcnt(4), issue at top-of-iter (race-free). Wave (qh,jh): S^T j-frag jh x
// q-frags 4qh..4qh+3; PV: all 8 q-frags x 32 ch. Emits bf16 numerator
// partials [c][128] + f32 ls partials (C-S bound => partials sum exact).
// ---------------------------------------------------------------------------
__global__ __launch_bounds__(512, 4) void attn_mfma(
    const u16* __restrict__ qT, const u8* __restrict__ Kg,
    const u8* __restrict__ Vg, const float* __restrict__ qnorm,
    const float* __restrict__ kmax, u16* __restrict__ numP,
    float* __restrict__ lsP)
{
    __shared__ __align__(16) u8 smem[69632];
    u8* const Vl = smem;             // 3 x 16384
    u8* const Kl = smem + 49152;     // 3 x 4096
    u8* const Pl = smem + 61440;     // 8192 (reduce overlays after loop)

    const int t = threadIdx.x;
    const int w = t >> 6, li = t & 15, g = (t >> 4) & 3;
    const int jh = w & 3, qh = w >> 2;
    const int cw = w * 32;
    const int swz = ((li >> 1) & 3) << 4;

    const int bid = blockIdx.x;                 // 400 = 4b x 25qt x 4js
    const int b = bid / 100, rem = bid % 100;
    const int qt = rem >> 2, js = rem & 3;
    const int i0 = qt * QT;
    const int jbeg = (NJT * js) / 4, jend = (NJT * (js + 1)) / 4;
    const int nIter = jend - jbeg;

    const u16* qTb = qT + (size_t)b * N_SP * CQ;
    const u8*  Kbb = Kg + (size_t)b * N_SP * 64;
    const u8*  Vbb = Vg + (size_t)b * NJT * 16384;
    const float kmb = kmax[b];
    const f32x4 zero = {0.f, 0.f, 0.f, 0.f};

    bf16x8 qf[4]; float mr[4];
    #pragma unroll
    for (int f = 0; f < 4; ++f) {
        int qr = i0 + (qh * 4 + f) * 16 + li;
        qr = qr < N_SP ? qr : N_SP - 1;         // clamp pad rows (qt==24)
        qf[f] = *(const bf16x8*)(qTb + (size_t)qr * CQ + 8 * g);
        mr[f] = qnorm[b * N_SP + qr] * kmb;
    }

    f32x4 acc[8][2];
    #pragma unroll
    for (int qq = 0; qq < 8; ++qq) { acc[qq][0] = zero; acc[qq][1] = zero; }
    float ls4[4] = {0.f, 0.f, 0.f, 0.f};

    #define ISSUE(jt_, s_) do {                                               \
        const u8* vsrc_ = Vbb + (size_t)(jt_) * 16384;                        \
        const u8* ksrc_ = Kbb + (size_t)(jt_) * 4096;                         \
        _Pragma("unroll")                                                     \
        for (int i_ = 0; i_ < 2; ++i_)                                        \
            dma16(vsrc_ + i_ * 8192 + t * 16,                                 \
                  Vl + (s_) * 16384 + i_ * 8192 + w * 1024);                  \
        _Pragma("unroll")                                                     \
        for (int i_ = 0; i_ < 2; ++i_)                                        \
            dma4(ksrc_ + i_ * 2048 + t * 4,                                   \
                 Kl + (s_) * 4096 + i_ * 2048 + w * 256);                     \
    } while (0)

    ISSUE(jbeg, 0);
    ISSUE(jbeg + 1, 1);

    // P write byte position: j' = jh*16 + 4g + r
    const int p0 = ((jh >> 1) & 1) * 8 + ((jh * 2 + (g >> 1)) & 3) * 16 + 4 * (g & 1);

    int cur = 0;
    for (int ii = 0; ii < nIter; ++ii) {
        const int it = jbeg + ii;
        asm volatile("s_waitcnt vmcnt(4) lgkmcnt(0)" ::: "memory");
        __builtin_amdgcn_s_barrier();
        asm volatile("" ::: "memory");

        {
            int jn = it + 2; if (jn > jend - 1) jn = jend - 1;
            int s2 = cur + 2; if (s2 >= 3) s2 -= 3;
            ISSUE(jn, s2);
        }

        // ---- S^T: j-frag jh x q-frags 4qh..4qh+3 ----
        const u8* Kc = Kl + cur * 4096;
        bf16x8 kf = *(const bf16x8*)(Kc + (jh * 16 + li) * 64 + ((16 * g) ^ swz));
        #pragma unroll
        for (int f = 0; f < 4; ++f) {
            f32x4 s = MFMA16(kf, qf[f], zero);
            float a0 = exp2f(s[0] - mr[f]), a1 = exp2f(s[1] - mr[f]);
            float a2 = exp2f(s[2] - mr[f]), a3 = exp2f(s[3] - mr[f]);
            ls4[f] += (a0 + a1) + (a2 + a3);
            int pk = __builtin_amdgcn_cvt_pk_bf8_f32(a0, a1, 0, false);
            pk = __builtin_amdgcn_cvt_pk_bf8_f32(a2, a3, pk, true);
            *(u32*)(Pl + ((qh * 4 + f) * 16 + li) * 64 + (p0 ^ swz)) = (u32)pk;
        }
        asm volatile("s_waitcnt lgkmcnt(0)" ::: "memory");
        __builtin_amdgcn_s_barrier();
        asm volatile("" ::: "memory");

        // ---- PV: 8 q-frags x this wave's 32 ch ----
        const u8* Vc = Vl + cur * 16384;
        __builtin_amdgcn_s_setprio(1);
        l64x2 v0 = *(const l64x2*)(Vc + (cw + li) * 64 + ((16 * g) ^ swz));
        l64x2 v1 = *(const l64x2*)(Vc + (cw + 16 + li) * 64 + ((16 * g) ^ swz));
        #pragma unroll
        for (int qq = 0; qq < 8; ++qq) {
            l64x2 pa = *(const l64x2*)(Pl + (qq * 16 + li) * 64 + ((16 * g) ^ swz));
            acc[qq][0] = MFMA8(pa[0], v0[0], acc[qq][0]);
            acc[qq][1] = MFMA8(pa[0], v1[0], acc[qq][1]);
            acc[qq][0] = MFMA8(pa[1], v0[1], acc[qq][0]);
            acc[qq][1] = MFMA8(pa[1], v1[1], acc[qq][1]);
        }
        __builtin_amdgcn_s_setprio(0);

        ++cur; if (cur == 3) cur = 0;
    }
    #undef ISSUE

    // ---- ls partials: reduce over g then jh-waves ----
    #pragma unroll
    for (int f = 0; f < 4; ++f) {
        ls4[f] += __shfl_xor(ls4[f], 16);
        ls4[f] += __shfl_xor(ls4[f], 32);
    }
    __syncthreads();                 // all PV reads of Pl done; reuse as reduce buf
    float* red = (float*)Pl;         // [8][64]
    if ((t & 63) < 16) {
        #pragma unroll
        for (int f = 0; f < 4; ++f) red[w * 64 + f * 16 + li] = ls4[f];
    }
    __syncthreads();
    if (t < QT) {
        const int qh2 = t >> 6, rowin = t & 63;
        float s = red[(qh2 * 4 + 0) * 64 + rowin] + red[(qh2 * 4 + 1) * 64 + rowin]
                + red[(qh2 * 4 + 2) * 64 + rowin] + red[(qh2 * 4 + 3) * 64 + rowin];
        lsP[(size_t)bid * QT + t] = s;
    }

    // ---- numerator partials: bf16, layout [c][128] ----
    u16* np = numP + (size_t)bid * QT * C_CH;
    #pragma unroll
    for (int qq = 0; qq < 8; ++qq) {
        #pragma unroll
        for (int cf = 0; cf < 2; ++cf) {
            const int c = cw + cf * 16 + li;
            ushort4 o;
            o.x = f2b(acc[qq][cf][0]); o.y = f2b(acc[qq][cf][1]);
            o.z = f2b(acc[qq][cf][2]); o.w = f2b(acc[qq][cf][3]);
            *(ushort4*)(np + c * QT + qq * 16 + 4 * g) = o;
        }
    }
}

// ---------------------------------------------------------------------------
// Combine: 200 blocks (4b x 25qt x 2 q-halves) x 256 thr. Sums 4 j-split
// partials, divides by ls, applies gamma/bound + residual.
// ---------------------------------------------------------------------------
__global__ __launch_bounds__(256) void attn_combine(
    const u16* __restrict__ numP, const float* __restrict__ lsP,
    const float* __restrict__ x, const float* __restrict__ gamma_p,
    float* __restrict__ out)
{
    const int bid = blockIdx.x;
    const int b = bid / 50, rem = bid % 50;
    const int qt = rem >> 1, hf = rem & 1;
    const int i0 = qt * QT;

    const int t = threadIdx.x;
    const int qloc = hf * 64 + (t & 63), cg = t >> 6;
    const int qglob = i0 + qloc;
    if (qglob >= N_SP) return;                // qt==24 upper half is pad

    const size_t blk0 = ((size_t)b * NQT + qt) * 4;
    float lsf = 0.f;
    #pragma unroll
    for (int s = 0; s < 4; ++s) lsf += lsP[(blk0 + s) * QT + qloc];
    const float rinv = gamma_p[0] * INV_BOUND / lsf;

    const u16* np = numP + blk0 * (size_t)(QT * C_CH);

    #pragma unroll 8
    for (int cc = 0; cc < 64; ++cc) {
        const int c = cg * 64 + cc;
        float num = b2f(np[c * QT + qloc])
                  + b2f(np[1 * QT * C_CH + c * QT + qloc])
                  + b2f(np[2 * QT * C_CH + c * QT + qloc])
                  + b2f(np[3 * QT * C_CH + c * QT + qloc]);
        const size_t base = ((size_t)b * C_CH + c) * N_SP + qglob;
        out[base] = num * rinv + x[base];
    }
}

// ---------------------------------------------------------------------------
extern "C" void kernel_launch(void* const* d_in, const int* in_sizes, int n_in,
                              void* d_out, int out_size, void* d_ws, size_t ws_size,
                              hipStream_t stream)
{
    const float* x  = (const float*)d_in[0];
    const float* Wq = (const float*)d_in[1];
    const float* bq = (const float*)d_in[2];
    const float* Wk = (const float*)d_in[3];
    const float* bk = (const float*)d_in[4];
    const float* Wv = (const float*)d_in[5];
    const float* bv = (const float*)d_in[6];
    const float* gm = (const float*)d_in[7];
    float* out = (float*)d_out;
    float* ws  = (float*)d_ws;

    float* scale = ws;                       // [0..3]
    float* kmax  = ws + 4;                   // [4..7]
    float* qnorm = ws + 8;                   // NB*N_SP
    u8* Wqb = (u8*)(ws + 8 + NB * N_SP);     // 16B-aligned
    u8* Wkb = Wqb + 32 * 512;
    u8* Wvb = Wkb + 32 * 512;
    u8* xT  = Wvb + 256 * 512;
    u16* qT = (u16*)(xT + (size_t)NB * N_SP * 512);
    u8* Kg  = (u8*)(qT + (size_t)NB * N_SP * CQ);
    u8* Vg  = Kg + (size_t)NB * N_SP * 64;
    u16* numP = (u16*)(Vg + (size_t)NB * NJT * 16384);   // 400*128*256 bf16
    float* lsP = (float*)(numP + (size_t)400 * QT * C_CH);

    stage1_kernel<<<865, 256, 0, stream>>>(x, Wq, Wk, Wv, xT, Wqb, Wkb, Wvb, scale, kmax);
    qkv_mfma<<<980, 256, 0, stream>>>(xT, Wqb, Wkb, Wvb, bq, bk, bv, scale, qT, Kg, Vg, qnorm, kmax);
    attn_mfma<<<NB * NQT * JSPL, 512, 0, stream>>>(qT, Kg, Vg, qnorm, kmax, numP, lsP);
    attn_combine<<<NB * NQT * 2, 256, 0, stream>>>(numP, lsP, x, gm, out);
}

// Round 16
// 87.971 us; speedup vs baseline: 1.0865x; 1.0865x over previous
//
#include <hip/hip_runtime.h>

#define N_SP 3136   // H*W = 49*64
#define C_CH 256
#define CQ   32
#define NB   4
#define JT   64     // attn j-tile
#define NJT  49     // j-tiles (exact)
#define QT   64     // attn q-tile (49 tiles exact)
// 1 / (exp(sqrt(3))*sqrt(3136/256) + 2*sqrt(6))
#define INV_BOUND 0.04051569f
#define LOG2E 1.44269504f

typedef __attribute__((ext_vector_type(8))) short bf16x8;
typedef __attribute__((ext_vector_type(4))) float f32x4;
typedef __attribute__((ext_vector_type(2))) long long l64x2;
typedef unsigned short u16;
typedef unsigned int   u32;
typedef unsigned char  u8;
typedef long long      l64;

#define MFMA16(a,b,c) __builtin_amdgcn_mfma_f32_16x16x32_bf16(a,b,c,0,0,0)
#define MFMA8(a,b,c)  __builtin_amdgcn_mfma_f32_16x16x32_bf8_fp8(a,b,c,0,0,0)

__device__ __forceinline__ u16 f2b(float f) {
    u32 u = __builtin_bit_cast(u32, f);
    u += 0x7fffu + ((u >> 16) & 1u);   // RTNE
    return (u16)(u >> 16);
}
__device__ __forceinline__ u8 f2fp8(float f) {
    return (u8)(__builtin_amdgcn_cvt_pk_fp8_f32(f, f, 0, false) & 0xff);
}
__device__ __forceinline__ void dma16(const void* g, void* l) {
    __builtin_amdgcn_global_load_lds((const __attribute__((address_space(1))) u32*)g,
                                     (__attribute__((address_space(3))) u32*)l, 16, 0, 0);
}
__device__ __forceinline__ void dma4(const void* g, void* l) {
    __builtin_amdgcn_global_load_lds((const __attribute__((address_space(1))) u32*)g,
                                     (__attribute__((address_space(3))) u32*)l, 4, 0, 0);
}

// ---------------------------------------------------------------------------
// stage1: xT transpose (0..783, XCD-affine: batch b -> XCDs {2b,2b+1}),
// W->bf16 (784..863), norm+scale+kmax0 (864). xT/W stored PRE-SWIZZLED:
// within each 512B row r, 16B slot at byte o lands at o ^ ((r&15)<<5).
// ---------------------------------------------------------------------------
__global__ __launch_bounds__(256) void stage1_kernel(
    const float* __restrict__ x, const float* __restrict__ Wq,
    const float* __restrict__ Wk, const float* __restrict__ Wv,
    u8* __restrict__ xT, u8* __restrict__ Wqb, u8* __restrict__ Wkb,
    u8* __restrict__ Wvb, float* __restrict__ scale_out,
    float* __restrict__ kmax)
{
    __shared__ float smem[64 * 65];
    const int t = threadIdx.x;
    const int bid = blockIdx.x;

    if (bid < 784) {
        float (*tile)[65] = (float(*)[65])smem;
        // XCD-affine: 784 = 98 slots x 8; batch b = xcd>>1, i = 2*slot+(xcd&1)
        const int xcd = bid & 7, slot = bid >> 3;
        const int b = xcd >> 1;
        const int i = slot * 2 + (xcd & 1);          // 0..195
        const int ct = i & 3, nt = i >> 2;           // 4 x 49
        const int c0 = ct * 64, n0 = nt * 64;
        const int cc = t >> 4, nn4 = (t & 15) * 4;
        #pragma unroll
        for (int k = 0; k < 4; ++k) {
            int cl = cc + k * 16;
            float4 v = *(const float4*)(x + (size_t)(b * C_CH + c0 + cl) * N_SP + n0 + nn4);
            tile[cl][nn4] = v.x; tile[cl][nn4 + 1] = v.y;
            tile[cl][nn4 + 2] = v.z; tile[cl][nn4 + 3] = v.w;
        }
        __syncthreads();
        const int c4 = (t & 15) * 4, nn = t >> 4;
        #pragma unroll
        for (int k = 0; k < 4; ++k) {
            int nl = nn + k * 16;
            ushort4 o;
            o.x = f2b(tile[c4 + 0][nl]); o.y = f2b(tile[c4 + 1][nl]);
            o.z = f2b(tile[c4 + 2][nl]); o.w = f2b(tile[c4 + 3][nl]);
            const int off = ((c0 + c4) * 2) ^ ((nl & 15) << 5);
            *(ushort4*)(xT + (size_t)(b * N_SP + n0 + nl) * 512 + off) = o;
        }
    } else if (bid < 864) {
        int idx = (bid - 784) * 256 + t;
        const float* src; u8* dst; int off;
        if (idx < 2048)      { src = Wq; dst = Wqb; off = idx; }
        else if (idx < 4096) { src = Wk; dst = Wkb; off = idx - 2048; }
        else                 { src = Wv; dst = Wvb; off = idx - 4096; }
        float4 v = *(const float4*)(src + off * 4);
        ushort4 o; o.x = f2b(v.x); o.y = f2b(v.y); o.z = f2b(v.z); o.w = f2b(v.w);
        const int row = off >> 6, inner = (off & 63) * 8;
        *(ushort4*)(dst + row * 512 + (inner ^ ((row & 15) << 5))) = o;
    } else {
        if (t < NB) kmax[t] = 0.f;
        float* red = smem;
        float u2 = 0.f;
        for (int i = t; i < CQ * C_CH; i += 256) { float w = Wq[i]; u2 += w * w; }
        red[t] = u2; __syncthreads();
        #pragma unroll
        for (int s = 128; s > 0; s >>= 1) { if (t < s) red[t] += red[t + s]; __syncthreads(); }
        float u2t = red[0]; __syncthreads();
        float vn2 = 0.f;
        for (int o = 0; o < CQ; ++o)   { float w = Wk[o * C_CH + t]; vn2 += w * w; }
        float wn2 = 0.f;
        for (int o = 0; o < C_CH; ++o) { float w = Wv[o * C_CH + t]; wn2 += w * w; }
        red[t] = fmaxf(vn2, wn2); __syncthreads();
        #pragma unroll
        for (int s = 128; s > 0; s >>= 1) { if (t < s) red[t] = fmaxf(red[t], red[t + s]); __syncthreads(); }
        if (t == 0) scale_out[0] = 1.0f / (sqrtf(u2t) * sqrtf(red[0]));
    }
}

// ---------------------------------------------------------------------------
// qkv (R12 body, XCD-affine grid 984 = 123 slots x 8): batch b = xcd>>1,
// i = 2*slot+(xcd&1) in 0..245 (i==245 idle); split = i/49, nt = i%49.
// DMA-staged x/W tiles -> LDS -> MFMA.
// ---------------------------------------------------------------------------
__global__ __launch_bounds__(256) void qkv_mfma(
    const u8* __restrict__ xT, const u8* __restrict__ Wqb,
    const u8* __restrict__ Wkb, const u8* __restrict__ Wvb,
    const float* __restrict__ bq, const float* __restrict__ bk,
    const float* __restrict__ bv, const float* __restrict__ scale_p,
    u16* __restrict__ qT, u8* __restrict__ Kg, u8* __restrict__ Vg,
    float* __restrict__ qnorm, float* __restrict__ kmax)
{
    __shared__ __align__(16) u8 xTl[32768];
    __shared__ __align__(16) u8 Wl[32768];

    const int t = threadIdx.x;
    const int xcd = blockIdx.x & 7, slot = blockIdx.x >> 3;
    const int b = xcd >> 1;
    const int i = slot * 2 + (xcd & 1);
    if (i >= 245) return;
    const int split = i / 49, nt = i % 49;
    const int w = t >> 6, lane = t & 63, li = t & 15, g = (t >> 4) & 3;
    const int n = nt * 64 + w * 16 + li;
    const int r0 = (split - 1) * 64;
    const f32x4 zero = {0.f, 0.f, 0.f, 0.f};

    {
        const u8* xsrc = xT + (size_t)(b * N_SP + nt * 64) * 512;
        #pragma unroll
        for (int k = 0; k < 8; ++k)
            dma16(xsrc + w * 8192 + k * 1024 + lane * 16, xTl + w * 8192 + k * 1024);
        if (split == 0) {
            #pragma unroll
            for (int k = 0; k < 4; ++k)
                dma16(Wqb + w * 4096 + k * 1024 + lane * 16, Wl + w * 4096 + k * 1024);
            #pragma unroll
            for (int k = 0; k < 4; ++k)
                dma16(Wkb + w * 4096 + k * 1024 + lane * 16, Wl + 16384 + w * 4096 + k * 1024);
        } else {
            const u8* wsrc = Wvb + (size_t)r0 * 512;
            #pragma unroll
            for (int k = 0; k < 8; ++k)
                dma16(wsrc + w * 8192 + k * 1024 + lane * 16, Wl + w * 8192 + k * 1024);
        }
    }
    asm volatile("s_waitcnt vmcnt(0)" ::: "memory");
    __syncthreads();

    const int swz = li << 5;
    bf16x8 xf[8];
    #pragma unroll
    for (int ks = 0; ks < 8; ++ks)
        xf[ks] = *(const bf16x8*)(xTl + (w * 16 + li) * 512 + ((ks * 64 + 16 * g) ^ swz));

    if (split == 0) {
        f32x4 aq0 = zero, aq1 = zero, ak0 = zero, ak1 = zero;
        #pragma unroll
        for (int ks = 0; ks < 8; ++ks) {
            const int o = (ks * 64 + 16 * g) ^ swz;
            bf16x8 w0 = *(const bf16x8*)(Wl + li * 512 + o);
            bf16x8 w1 = *(const bf16x8*)(Wl + (16 + li) * 512 + o);
            bf16x8 w2 = *(const bf16x8*)(Wl + 16384 + li * 512 + o);
            bf16x8 w3 = *(const bf16x8*)(Wl + 16384 + (16 + li) * 512 + o);
            aq0 = MFMA16(w0, xf[ks], aq0);
            aq1 = MFMA16(w1, xf[ks], aq1);
            ak0 = MFMA16(w2, xf[ks], ak0);
            ak1 = MFMA16(w3, xf[ks], ak1);
        }
        const float scf = scale_p[0] * LOG2E;
        f32x4 bq0 = *(const f32x4*)(bq + 4 * g);
        f32x4 bq1 = *(const f32x4*)(bq + 16 + 4 * g);
        f32x4 bk0 = *(const f32x4*)(bk + 4 * g);
        f32x4 bk1 = *(const f32x4*)(bk + 16 + 4 * g);
        float qn2 = 0.f, kn2 = 0.f;
        ushort4 s0, s1;
        #pragma unroll
        for (int r = 0; r < 4; ++r) {
            float q0 = (aq0[r] + bq0[r]) * scf;
            float q1 = (aq1[r] + bq1[r]) * scf;
            qn2 += q0 * q0 + q1 * q1;
            ((u16*)&s0)[r] = f2b(q0); ((u16*)&s1)[r] = f2b(q1);
        }
        *(ushort4*)(qT + (size_t)(b * N_SP + n) * CQ + 4 * g)      = s0;
        *(ushort4*)(qT + (size_t)(b * N_SP + n) * CQ + 16 + 4 * g) = s1;
        #pragma unroll
        for (int r = 0; r < 4; ++r) {
            float k0 = ak0[r] + bk0[r];
            float k1 = ak1[r] + bk1[r];
            kn2 += k0 * k0 + k1 * k1;
            ((u16*)&s0)[r] = f2b(k0); ((u16*)&s1)[r] = f2b(k1);
        }
        u8* krow = Kg + ((size_t)b * N_SP + n) * 64;
        const int swn = ((n >> 1) & 3) << 4;
        *(ushort4*)(krow + ((8 * g) ^ swn))      = s0;
        *(ushort4*)(krow + ((32 + 8 * g) ^ swn)) = s1;

        qn2 += __shfl_xor(qn2, 16); qn2 += __shfl_xor(qn2, 32);
        kn2 += __shfl_xor(kn2, 16); kn2 += __shfl_xor(kn2, 32);
        if (g == 0) qnorm[b * N_SP + n] = sqrtf(qn2);
        float kn = sqrtf(kn2);
        #pragma unroll
        for (int d = 1; d < 16; d <<= 1) kn = fmaxf(kn, __shfl_xor(kn, d));
        if ((t & 63) == 0) atomicMax((int*)(kmax + b), __float_as_int(kn));
    } else {
        f32x4 a[4] = {zero, zero, zero, zero};
        #pragma unroll
        for (int ks = 0; ks < 8; ++ks) {
            const int o = (ks * 64 + 16 * g) ^ swz;
            #pragma unroll
            for (int fr = 0; fr < 4; ++fr) {
                bf16x8 wf = *(const bf16x8*)(Wl + (fr * 16 + li) * 512 + o);
                a[fr] = MFMA16(wf, xf[ks], a[fr]);
            }
        }
        const int jj = w * 16 + li;
        const int p = ((jj >> 5) & 1) * 8 + ((jj >> 3) & 3) * 16 + (jj & 7);
        u8* vtile = Vg + (size_t)(b * NJT + nt) * 16384;
        #pragma unroll
        for (int fr = 0; fr < 4; ++fr) {
            f32x4 bb = *(const f32x4*)(bv + r0 + fr * 16 + 4 * g);
            #pragma unroll
            for (int r = 0; r < 4; ++r) {
                const int c = r0 + fr * 16 + 4 * g + r;
                vtile[c * 64 + (p ^ (((c >> 1) & 3) << 4))] = f2fp8(a[fr][r] + bb[r]);
            }
        }
    }
}

// ---------------------------------------------------------------------------
// Attention (R12 body, XCD-affine grid 200 = 25 slots x 8): batch b = xcd>>1,
// qt = 2*slot+(xcd&1) in 0..49 (qt==49 idle). Ring-4 depth-3 DMA, vmcnt(8),
// coalesced V/K tiles, b128 LDS reads, 2-way-max swizzles, direct epilogue.
// ---------------------------------------------------------------------------
__global__ __launch_bounds__(512) void attn_mfma(
    const u16* __restrict__ qT, const u8* __restrict__ Kg,
    const u8* __restrict__ Vg, const float* __restrict__ x,
    const float* __restrict__ gamma_p, const float* __restrict__ qnorm,
    const float* __restrict__ kmax, float* __restrict__ out)
{
    __shared__ __align__(16) u8 smem[86016];
    u8* const Vl = smem;             // 4 x 16384
    u8* const Kl = smem + 65536;     // 4 x 4096
    u8* const Pl = smem + 81920;     // 4096 (reduce overlays here after loop)

    const int t = threadIdx.x;
    const int w = t >> 6, li = t & 15, g = (t >> 4) & 3;
    const int jh = w & 3, qh = w >> 2;
    const int cw = w * 32;
    const int swz = ((li >> 1) & 3) << 4;

    const int xcd = blockIdx.x & 7, slot = blockIdx.x >> 3;
    const int b  = xcd >> 1;
    const int qt = slot * 2 + (xcd & 1);
    if (qt >= NJT) return;
    const int i0 = qt * QT;

    const u16* qTb = qT + (size_t)b * N_SP * CQ;
    const u8*  Kbb = Kg + (size_t)b * N_SP * 64;
    const u8*  Vbb = Vg + (size_t)b * NJT * 16384;
    const float kmb = kmax[b];
    const f32x4 zero = {0.f, 0.f, 0.f, 0.f};

    const int qA = 2 * qh, qB = 2 * qh + 1;
    const bf16x8 qfA = *(const bf16x8*)(qTb + (size_t)(i0 + qA * 16 + li) * CQ + 8 * g);
    const bf16x8 qfB = *(const bf16x8*)(qTb + (size_t)(i0 + qB * 16 + li) * CQ + 8 * g);
    const float mrA = qnorm[b * N_SP + i0 + qA * 16 + li] * kmb;
    const float mrB = qnorm[b * N_SP + i0 + qB * 16 + li] * kmb;

    f32x4 acc[4][2];
    #pragma unroll
    for (int qq = 0; qq < 4; ++qq) { acc[qq][0] = zero; acc[qq][1] = zero; }
    float lsA = 0.f, lsB = 0.f;

    #define ISSUE(jt_, s_) do {                                               \
        const u8* vsrc_ = Vbb + (size_t)(jt_) * 16384;                        \
        const u8* ksrc_ = Kbb + (size_t)(jt_) * 4096;                         \
        _Pragma("unroll")                                                     \
        for (int i_ = 0; i_ < 2; ++i_)                                        \
            dma16(vsrc_ + i_ * 8192 + t * 16,                                 \
                  Vl + (s_) * 16384 + i_ * 8192 + w * 1024);                  \
        _Pragma("unroll")                                                     \
        for (int i_ = 0; i_ < 2; ++i_)                                        \
            dma4(ksrc_ + i_ * 2048 + t * 4,                                   \
                 Kl + (s_) * 4096 + i_ * 2048 + w * 256);                     \
    } while (0)

    ISSUE(0, 0);
    ISSUE(1, 1);
    ISSUE(2, 2);

    // P write position (fixed per thread): j' = jh*16 + 4g + r
    const int p0 = ((jh >> 1) & 1) * 8 + ((jh * 2 + (g >> 1)) & 3) * 16 + 4 * (g & 1);

    for (int it = 0; it < NJT; ++it) {
        const int cur = it & 3;
        asm volatile("s_waitcnt vmcnt(8) lgkmcnt(0)" ::: "memory");
        __builtin_amdgcn_s_barrier();
        asm volatile("" ::: "memory");

        {
            int jn = it + 3; if (jn > NJT - 1) jn = NJT - 1;
            ISSUE(jn, (cur + 3) & 3);
        }

        // ---- S^T: j-frag jh x q-frags {qA, qB} ----
        const u8* Kc = Kl + cur * 4096;
        bf16x8 kf = *(const bf16x8*)(Kc + (jh * 16 + li) * 64 + ((16 * g) ^ swz));
        f32x4 sA = MFMA16(kf, qfA, zero);
        f32x4 sB = MFMA16(kf, qfB, zero);
        {
            float a0 = exp2f(sA[0] - mrA), a1 = exp2f(sA[1] - mrA);
            float a2 = exp2f(sA[2] - mrA), a3 = exp2f(sA[3] - mrA);
            lsA += (a0 + a1) + (a2 + a3);
            int pk = __builtin_amdgcn_cvt_pk_bf8_f32(a0, a1, 0, false);
            pk = __builtin_amdgcn_cvt_pk_bf8_f32(a2, a3, pk, true);
            *(u32*)(Pl + (qA * 16 + li) * 64 + (p0 ^ swz)) = (u32)pk;
            float b0 = exp2f(sB[0] - mrB), b1 = exp2f(sB[1] - mrB);
            float b2 = exp2f(sB[2] - mrB), b3 = exp2f(sB[3] - mrB);
            lsB += (b0 + b1) + (b2 + b3);
            pk = __builtin_amdgcn_cvt_pk_bf8_f32(b0, b1, 0, false);
            pk = __builtin_amdgcn_cvt_pk_bf8_f32(b2, b3, pk, true);
            *(u32*)(Pl + (qB * 16 + li) * 64 + (p0 ^ swz)) = (u32)pk;
        }
        asm volatile("s_waitcnt lgkmcnt(0)" ::: "memory");
        __builtin_amdgcn_s_barrier();
        asm volatile("" ::: "memory");

        // ---- PV: all 4 q-frags x this wave's 32 ch (b128 = both ks) ----
        const u8* Vc = Vl + cur * 16384;
        __builtin_amdgcn_s_setprio(1);
        l64x2 pa0 = *(const l64x2*)(Pl + (0 * 16 + li) * 64 + ((16 * g) ^ swz));
        l64x2 pa1 = *(const l64x2*)(Pl + (1 * 16 + li) * 64 + ((16 * g) ^ swz));
        l64x2 pa2 = *(const l64x2*)(Pl + (2 * 16 + li) * 64 + ((16 * g) ^ swz));
        l64x2 pa3 = *(const l64x2*)(Pl + (3 * 16 + li) * 64 + ((16 * g) ^ swz));
        l64x2 v0  = *(const l64x2*)(Vc + (cw + li) * 64 + ((16 * g) ^ swz));
        l64x2 v1  = *(const l64x2*)(Vc + (cw + 16 + li) * 64 + ((16 * g) ^ swz));
        acc[0][0] = MFMA8(pa0[0], v0[0], acc[0][0]);
        acc[0][1] = MFMA8(pa0[0], v1[0], acc[0][1]);
        acc[1][0] = MFMA8(pa1[0], v0[0], acc[1][0]);
        acc[1][1] = MFMA8(pa1[0], v1[0], acc[1][1]);
        acc[2][0] = MFMA8(pa2[0], v0[0], acc[2][0]);
        acc[2][1] = MFMA8(pa2[0], v1[0], acc[2][1]);
        acc[3][0] = MFMA8(pa3[0], v0[0], acc[3][0]);
        acc[3][1] = MFMA8(pa3[0], v1[0], acc[3][1]);
        acc[0][0] = MFMA8(pa0[1], v0[1], acc[0][0]);
        acc[0][1] = MFMA8(pa0[1], v1[1], acc[0][1]);
        acc[1][0] = MFMA8(pa1[1], v0[1], acc[1][0]);
        acc[1][1] = MFMA8(pa1[1], v1[1], acc[1][1]);
        acc[2][0] = MFMA8(pa2[1], v0[1], acc[2][0]);
        acc[2][1] = MFMA8(pa2[1], v1[1], acc[2][1]);
        acc[3][0] = MFMA8(pa3[1], v0[1], acc[3][0]);
        acc[3][1] = MFMA8(pa3[1], v1[1], acc[3][1]);
        __builtin_amdgcn_s_setprio(0);
    }
    #undef ISSUE

    // ---- denominators (reduce buffers overlay P region) ----
    lsA += __shfl_xor(lsA, 16); lsA += __shfl_xor(lsA, 32);
    lsB += __shfl_xor(lsB, 16); lsB += __shfl_xor(lsB, 32);
    __syncthreads();
    float* red       = (float*)Pl;
    float* red_final = (float*)(Pl + 1024);
    if ((t & 63) < 16) {
        red[w * 32 + li]      = lsA;
        red[w * 32 + 16 + li] = lsB;
    }
    __syncthreads();
    if (t < 64) {
        const int h = t >> 4, l2 = t & 15;
        float s = 0.f;
        #pragma unroll
        for (int jw = 0; jw < 4; ++jw)
            s += red[((h >> 1) * 4 + jw) * 32 + (h & 1) * 16 + l2];
        red_final[t] = s;
    }
    __syncthreads();

    // ---- epilogue ----
    const float gsc = gamma_p[0] * INV_BOUND;
    #pragma unroll
    for (int qq = 0; qq < 4; ++qq) {
        f32x4 lsv = *(const f32x4*)(red_final + qq * 16 + 4 * g);
        f32x4 rinv;
        #pragma unroll
        for (int r = 0; r < 4; ++r) rinv[r] = gsc / lsv[r];
        #pragma unroll
        for (int cf = 0; cf < 2; ++cf) {
            const int c = cw + cf * 16 + li;
            const size_t base = ((size_t)b * C_CH + c) * N_SP + i0 + qq * 16 + 4 * g;
            float4 xv = *(const float4*)(x + base);
            float4 o;
            o.x = acc[qq][cf][0] * rinv[0] + xv.x;
            o.y = acc[qq][cf][1] * rinv[1] + xv.y;
            o.z = acc[qq][cf][2] * rinv[2] + xv.z;
            o.w = acc[qq][cf][3] * rinv[3] + xv.w;
            *(float4*)(out + base) = o;
        }
    }
}

// ---------------------------------------------------------------------------
extern "C" void kernel_launch(void* const* d_in, const int* in_sizes, int n_in,
                              void* d_out, int out_size, void* d_ws, size_t ws_size,
                              hipStream_t stream)
{
    const float* x  = (const float*)d_in[0];
    const float* Wq = (const float*)d_in[1];
    const float* bq = (const float*)d_in[2];
    const float* Wk = (const float*)d_in[3];
    const float* bk = (const float*)d_in[4];
    const float* Wv = (const float*)d_in[5];
    const float* bv = (const float*)d_in[6];
    const float* gm = (const float*)d_in[7];
    float* out = (float*)d_out;
    float* ws  = (float*)d_ws;

    float* scale = ws;                       // [0..3]
    float* kmax  = ws + 4;                   // [4..7]
    float* qnorm = ws + 8;                   // NB*N_SP
    u8* Wqb = (u8*)(ws + 8 + NB * N_SP);     // 16B-aligned
    u8* Wkb = Wqb + 32 * 512;
    u8* Wvb = Wkb + 32 * 512;
    u8* xT  = Wvb + 256 * 512;
    u16* qT = (u16*)(xT + (size_t)NB * N_SP * 512);
    u8* Kg  = (u8*)(qT + (size_t)NB * N_SP * CQ);
    u8* Vg  = Kg + (size_t)NB * N_SP * 64;

    stage1_kernel<<<865, 256, 0, stream>>>(x, Wq, Wk, Wv, xT, Wqb, Wkb, Wvb, scale, kmax);
    qkv_mfma<<<984, 256, 0, stream>>>(xT, Wqb, Wkb, Wvb, bq, bk, bv, scale, qT, Kg, Vg, qnorm, kmax);
    attn_mfma<<<200, 512, 0, stream>>>(qT, Kg, Vg, x, gm, qnorm, kmax, out);
}